// Round 1
// baseline (921.939 us; speedup 1.0000x reference)
//
#include <hip/hip_runtime.h>
#include <hip/hip_bf16.h>
#include <math.h>

typedef __attribute__((ext_vector_type(8))) short short8;
typedef __attribute__((ext_vector_type(4))) float floatx4;

__device__ __forceinline__ float bf2f(unsigned int u) {
    union { unsigned int i; float f; } c; c.i = u << 16; return c.f;
}
__device__ __forceinline__ unsigned short f2bf(float f) {
    unsigned int x = __builtin_bit_cast(unsigned int, f);
    unsigned int r = (x + 0x7fffu + ((x >> 16) & 1u)) >> 16;
    return (unsigned short)r;
}
__device__ __forceinline__ float elu1(float x) { return x > 0.f ? x + 1.f : __expf(x); }
__device__ __forceinline__ float gelu_exact(float x) {
    return 0.5f * x * (1.f + erff(x * 0.70710678118654752f));
}

__device__ __forceinline__ void async_cp16(const void* g, void* l) {
    __builtin_amdgcn_global_load_lds(
        (const __attribute__((address_space(1))) unsigned int*)g,
        (__attribute__((address_space(3))) unsigned int*)l, 16, 0, 0);
}

// ---------------- zero fill ----------------
__global__ void zero_f32(float* __restrict__ p, int n) {
    int i = blockIdx.x * 256 + threadIdx.x;
    if (i < n) p[i] = 0.f;
}

// ---------------- weight convert + transpose: fp32 [K,N] -> bf16 [N,K] ----------------
__global__ void wcvt(const float* __restrict__ in, unsigned short* __restrict__ outp,
                     int K, int N) {
    __shared__ float tile[32][33];
    const int n0 = blockIdx.x * 32, k0 = blockIdx.y * 32;
    const int tx = threadIdx.x, ty = threadIdx.y;   // 32 x 8
#pragma unroll
    for (int i = 0; i < 4; i++)
        tile[ty + 8 * i][tx] = in[(size_t)(k0 + ty + 8 * i) * N + n0 + tx];
    __syncthreads();
#pragma unroll
    for (int i = 0; i < 4; i++)
        outp[(size_t)(n0 + ty + 8 * i) * K + k0 + tx] = f2bf(tile[tx][ty + 8 * i]);
}

// ---------------- LayerNorm: fp32 [M,1024] -> bf16 [M,1024] ----------------
__global__ __launch_bounds__(256)
void ln_kernel(const float* __restrict__ x, const float* __restrict__ g,
               const float* __restrict__ be, unsigned short* __restrict__ out) {
    const int row = blockIdx.x;
    const int t = threadIdx.x;
    const float4 v = *(const float4*)(x + (size_t)row * 1024 + t * 4);
    float s = v.x + v.y + v.z + v.w;
    float s2 = v.x * v.x + v.y * v.y + v.z * v.z + v.w * v.w;
#pragma unroll
    for (int off = 32; off > 0; off >>= 1) {
        s += __shfl_down(s, off);
        s2 += __shfl_down(s2, off);
    }
    __shared__ float red[8];
    __shared__ float stat[2];
    const int w = t >> 6, l = t & 63;
    if (l == 0) { red[w] = s; red[4 + w] = s2; }
    __syncthreads();
    if (t == 0) {
        float S = red[0] + red[1] + red[2] + red[3];
        float S2 = red[4] + red[5] + red[6] + red[7];
        float mu = S * (1.f / 1024.f);
        float var = S2 * (1.f / 1024.f) - mu * mu;
        stat[0] = mu;
        stat[1] = rsqrtf(var + 1e-5f);
    }
    __syncthreads();
    const float mu = stat[0], rs = stat[1];
    const float4 gv = *(const float4*)(g + t * 4);
    const float4 bv = *(const float4*)(be + t * 4);
    unsigned int o0 = f2bf((v.x - mu) * rs * gv.x + bv.x);
    unsigned int o1 = f2bf((v.y - mu) * rs * gv.y + bv.y);
    unsigned int o2 = f2bf((v.z - mu) * rs * gv.z + bv.z);
    unsigned int o3 = f2bf((v.w - mu) * rs * gv.w + bv.w);
    uint2 pk;
    pk.x = o0 | (o1 << 16);
    pk.y = o2 | (o3 << 16);
    *(uint2*)(out + (size_t)row * 1024 + t * 4) = pk;
}

// ---------------- GEMM: C[M,N] = A[M,K](bf16) * B[N,K](bf16)^T + bias, fused epilogue ----
// EPI 0: bias; cols<2048 get elu+1 (qkv feature map); store bf16
// EPI 1: bias + residual(fp32 [M,N]); store fp32
// EPI 2: bias + exact gelu; store bf16
template <int EPI>
__global__ __launch_bounds__(256, 2)
void gemm_bt(const unsigned short* __restrict__ A, const unsigned short* __restrict__ B,
             const float* __restrict__ bias, const float* __restrict__ resid,
             unsigned short* __restrict__ Cbf, float* __restrict__ Cf32,
             int N, int K) {
    __shared__ unsigned short At[128 * 32];
    __shared__ unsigned short Bt[128 * 32];
    const int t = threadIdx.x;
    const int l = t & 63;
    const int w = t >> 6;
    const int m0 = blockIdx.y * 128;
    const int n0 = blockIdx.x * 128;
    const int wm = (w >> 1) * 64;
    const int wn = (w & 1) * 64;

    floatx4 acc[4][4];
    const floatx4 zz = {0.f, 0.f, 0.f, 0.f};
#pragma unroll
    for (int i = 0; i < 4; i++)
#pragma unroll
        for (int j = 0; j < 4; j++) acc[i][j] = zz;

    // staging: thread t covers LDS elems [t*8, t*8+8); row=t>>2, col=(t&3)*8
    const int sr = t >> 2;
    const int sc = (t & 3) << 3;
    const unsigned short* ag = A + (size_t)(m0 + sr) * K + sc;
    const unsigned short* ag2 = ag + (size_t)64 * K;
    const unsigned short* bg = B + (size_t)(n0 + sr) * K + sc;
    const unsigned short* bg2 = bg + (size_t)64 * K;
    unsigned short* la = At + t * 8;
    unsigned short* la2 = At + 2048 + t * 8;
    unsigned short* lb = Bt + t * 8;
    unsigned short* lb2 = Bt + 2048 + t * 8;

    const int fr = l & 15;
    const int fo = (l >> 4) << 3;

    for (int k0 = 0; k0 < K; k0 += 32) {
        async_cp16(ag + k0, la);
        async_cp16(ag2 + k0, la2);
        async_cp16(bg + k0, lb);
        async_cp16(bg2 + k0, lb2);
        __syncthreads();
        short8 af[4], bf[4];
#pragma unroll
        for (int i = 0; i < 4; i++)
            af[i] = *(const short8*)(At + (wm + i * 16 + fr) * 32 + fo);
#pragma unroll
        for (int i = 0; i < 4; i++)
            bf[i] = *(const short8*)(Bt + (wn + i * 16 + fr) * 32 + fo);
#pragma unroll
        for (int i = 0; i < 4; i++)
#pragma unroll
            for (int j = 0; j < 4; j++)
                acc[i][j] = __builtin_amdgcn_mfma_f32_16x16x32_bf16(af[i], bf[j], acc[i][j], 0, 0, 0);
        __syncthreads();
    }

    // epilogue: D[m][n] lane map: n = l&15, m = (l>>4)*4 + reg
    const int er = (l >> 4) << 2;
    const int ec = l & 15;
#pragma unroll
    for (int j = 0; j < 4; j++) {
        const int col = n0 + wn + j * 16 + ec;
        const float bb = bias[col];
#pragma unroll
        for (int i = 0; i < 4; i++) {
            const int rowb = m0 + wm + i * 16 + er;
#pragma unroll
            for (int r = 0; r < 4; r++) {
                const int row = rowb + r;
                float v = acc[i][j][r] + bb;
                const size_t idx = (size_t)row * N + col;
                if (EPI == 0) {
                    if (col < 2048) v = elu1(v);
                    Cbf[idx] = f2bf(v);
                } else if (EPI == 1) {
                    Cf32[idx] = v + resid[idx];
                } else {
                    Cbf[idx] = f2bf(gelu_exact(v));
                }
            }
        }
    }
}

// ---------------- kv[e][d] = sum_n kf[n][e] v[n][d]; z[e] = sum_n kf[n][e] ----------------
// qkv layout: [16384, 3072] bf16, q=0:1024 (elu'd), k=1024:2048 (elu'd), v=2048:3072
__global__ __launch_bounds__(256)
void kv_kernel(const unsigned short* __restrict__ qkv, float* __restrict__ kvz) {
    const int bh = blockIdx.x;     // 0..63
    const int chunk = blockIdx.y;  // 0..7, 512 tokens each
    const int b = bh >> 4, h = bh & 15;
    const int t = threadIdx.x;
    __shared__ float kf[64][68];
    __shared__ float vv[64][68];
    const int te = t >> 4, td = t & 15;
    float acc[4][4];
#pragma unroll
    for (int i = 0; i < 4; i++)
#pragma unroll
        for (int j = 0; j < 4; j++) acc[i][j] = 0.f;
    float zacc = 0.f;
    const size_t base = (size_t)b * 4096 * 3072 + (size_t)chunk * 512 * 3072;
    const int koff = 1024 + h * 64;
    const int voff = 2048 + h * 64;
    const int rl = t >> 3, seg = t & 7;

    for (int s = 0; s < 8; s++) {
#pragma unroll
        for (int p = 0; p < 2; p++) {
            const int nl = p * 32 + rl;
            const unsigned short* rp = qkv + base + (size_t)(s * 64 + nl) * 3072;
            const uint4 kd = *(const uint4*)(rp + koff + seg * 8);
            const uint4 vd = *(const uint4*)(rp + voff + seg * 8);
            float* kdst = &kf[nl][seg * 8];
            float* vdst = &vv[nl][seg * 8];
            kdst[0] = bf2f(kd.x & 0xffff); kdst[1] = bf2f(kd.x >> 16);
            kdst[2] = bf2f(kd.y & 0xffff); kdst[3] = bf2f(kd.y >> 16);
            kdst[4] = bf2f(kd.z & 0xffff); kdst[5] = bf2f(kd.z >> 16);
            kdst[6] = bf2f(kd.w & 0xffff); kdst[7] = bf2f(kd.w >> 16);
            vdst[0] = bf2f(vd.x & 0xffff); vdst[1] = bf2f(vd.x >> 16);
            vdst[2] = bf2f(vd.y & 0xffff); vdst[3] = bf2f(vd.y >> 16);
            vdst[4] = bf2f(vd.z & 0xffff); vdst[5] = bf2f(vd.z >> 16);
            vdst[6] = bf2f(vd.w & 0xffff); vdst[7] = bf2f(vd.w >> 16);
        }
        __syncthreads();
        for (int n = 0; n < 64; n++) {
            const float4 kk = *(const float4*)&kf[n][te * 4];
            const float4 vn = *(const float4*)&vv[n][td * 4];
            const float ka[4] = {kk.x, kk.y, kk.z, kk.w};
            const float va[4] = {vn.x, vn.y, vn.z, vn.w};
#pragma unroll
            for (int i = 0; i < 4; i++)
#pragma unroll
                for (int j = 0; j < 4; j++) acc[i][j] = fmaf(ka[i], va[j], acc[i][j]);
        }
        if (t < 64) {
            for (int n = 0; n < 64; n++) zacc += kf[n][t];
        }
        __syncthreads();
    }
    float* kvp = kvz + bh * 4160;
#pragma unroll
    for (int i = 0; i < 4; i++)
#pragma unroll
        for (int j = 0; j < 4; j++)
            atomicAdd(&kvp[(te * 4 + i) * 64 + td * 4 + j], acc[i][j]);
    if (t < 64) atomicAdd(&kvp[4096 + t], zacc);
}

// ---------------- y[n][d] = (sum_e qf[n][e] kv[e][d]) / max(qf.z, eps), store bf16 -------
__global__ __launch_bounds__(256)
void y_kernel(const unsigned short* __restrict__ qkv, const float* __restrict__ kvz,
              unsigned short* __restrict__ y) {
    const int bh = blockIdx.x, chunk = blockIdx.y;  // 64 x 32 (128 tokens/chunk)
    const int b = bh >> 4, h = bh & 15;
    const int t = threadIdx.x;
    __shared__ float kv[64][68];
    __shared__ float zs[64];
    __shared__ float qf[16][68];
    const float* kvp = kvz + bh * 4160;
#pragma unroll
    for (int p = 0; p < 4; p++) {
        const int f = (t + p * 256) * 4;
        const float4 v4 = *(const float4*)(kvp + f);
        *(float4*)&kv[f >> 6][f & 63] = v4;
    }
    if (t < 16) *(float4*)&zs[t * 4] = *(const float4*)(kvp + 4096 + t * 4);
    __syncthreads();
    const int nl = t >> 4, td = t & 15;
    const size_t base = (size_t)b * 4096 * 3072 + (size_t)chunk * 128 * 3072;
    const int qoff = h * 64;
    for (int s = 0; s < 8; s++) {
        if (t < 128) {
            const int r = t >> 3, seg = t & 7;
            const uint4 qd = *(const uint4*)(qkv + base + (size_t)(s * 16 + r) * 3072 + qoff + seg * 8);
            float* qdst = &qf[r][seg * 8];
            qdst[0] = bf2f(qd.x & 0xffff); qdst[1] = bf2f(qd.x >> 16);
            qdst[2] = bf2f(qd.y & 0xffff); qdst[3] = bf2f(qd.y >> 16);
            qdst[4] = bf2f(qd.z & 0xffff); qdst[5] = bf2f(qd.z >> 16);
            qdst[6] = bf2f(qd.w & 0xffff); qdst[7] = bf2f(qd.w >> 16);
        }
        __syncthreads();
        float a0 = 0.f, a1 = 0.f, a2 = 0.f, a3 = 0.f, den = 0.f;
        for (int e = 0; e < 64; e++) {
            const float q = qf[nl][e];
            const float4 kvv = *(const float4*)&kv[e][td * 4];
            a0 = fmaf(q, kvv.x, a0);
            a1 = fmaf(q, kvv.y, a1);
            a2 = fmaf(q, kvv.z, a2);
            a3 = fmaf(q, kvv.w, a3);
            den = fmaf(q, zs[e], den);
        }
        const float inv = 1.f / fmaxf(den, 1e-6f);
        const int tok = b * 4096 + chunk * 128 + s * 16 + nl;
        unsigned int o0 = f2bf(a0 * inv), o1 = f2bf(a1 * inv);
        unsigned int o2 = f2bf(a2 * inv), o3 = f2bf(a3 * inv);
        uint2 pk;
        pk.x = o0 | (o1 << 16);
        pk.y = o2 | (o3 << 16);
        *(uint2*)(y + (size_t)tok * 1024 + h * 64 + td * 4) = pk;
        __syncthreads();
    }
}

extern "C" void kernel_launch(void* const* d_in, const int* in_sizes, int n_in,
                              void* d_out, int out_size, void* d_ws, size_t ws_size,
                              hipStream_t stream) {
    const float* src   = (const float*)d_in[0];
    const float* qkv_w = (const float*)d_in[1];
    const float* qkv_b = (const float*)d_in[2];
    const float* out_w = (const float*)d_in[3];
    const float* out_b = (const float*)d_in[4];
    const float* w1    = (const float*)d_in[5];
    const float* b1    = (const float*)d_in[6];
    const float* w2    = (const float*)d_in[7];
    const float* b2    = (const float*)d_in[8];
    const float* g1    = (const float*)d_in[9];
    const float* be1   = (const float*)d_in[10];
    const float* g2    = (const float*)d_in[11];
    const float* be2   = (const float*)d_in[12];
    float* outp = (float*)d_out;

    char* ws = (char*)d_ws;
    unsigned short* qkvwT = (unsigned short*)(ws + 0);          // 3072x1024 bf16
    unsigned short* outwT = (unsigned short*)(ws + 6291456);    // 1024x1024 bf16
    unsigned short* w1T   = (unsigned short*)(ws + 8388608);    // 4096x1024 bf16
    unsigned short* w2T   = (unsigned short*)(ws + 16777216);   // 1024x4096 bf16
    unsigned short* bufA  = (unsigned short*)(ws + 25165824);   // qkv [16384,3072] then h [16384,4096] bf16
    unsigned short* bufB  = (unsigned short*)(ws + 159383552);  // ln1 -> y -> ln2 [16384,1024] bf16
    float*          xbuf  = (float*)(ws + 192937984);           // x [16384,1024] fp32
    float*          kvz   = (float*)(ws + 260046848);           // 64*(64*64+64) fp32

    // weights -> bf16 transposed [N,K]
    wcvt<<<dim3(3072 / 32, 1024 / 32), dim3(32, 8), 0, stream>>>(qkv_w, qkvwT, 1024, 3072);
    wcvt<<<dim3(1024 / 32, 1024 / 32), dim3(32, 8), 0, stream>>>(out_w, outwT, 1024, 1024);
    wcvt<<<dim3(4096 / 32, 1024 / 32), dim3(32, 8), 0, stream>>>(w1, w1T, 1024, 4096);
    wcvt<<<dim3(1024 / 32, 4096 / 32), dim3(32, 8), 0, stream>>>(w2, w2T, 4096, 1024);
    zero_f32<<<(266240 + 255) / 256, 256, 0, stream>>>(kvz, 266240);

    // 1) ln1 = LN(src)
    ln_kernel<<<16384, 256, 0, stream>>>(src, g1, be1, bufB);
    // 2) qkv = ln1 @ qkv_w + b (elu+1 fused on q,k cols), bf16
    gemm_bt<0><<<dim3(24, 128), 256, 0, stream>>>(bufB, qkvwT, qkv_b, nullptr, bufA, nullptr, 3072, 1024);
    // 3) kv, z aggregation
    kv_kernel<<<dim3(64, 8), 256, 0, stream>>>(bufA, kvz);
    // 4) y = qf@kv / den  (bf16, [16384,1024] in [b,n,h,d] order)
    y_kernel<<<dim3(64, 32), 256, 0, stream>>>(bufA, kvz, bufB);
    // 5) x = y @ out_w + out_b + src  (fp32)
    gemm_bt<1><<<dim3(8, 128), 256, 0, stream>>>(bufB, outwT, out_b, src, nullptr, xbuf, 1024, 1024);
    // 6) ln2 = LN(x)
    ln_kernel<<<16384, 256, 0, stream>>>(xbuf, g2, be2, bufB);
    // 7) h = gelu(ln2 @ w1 + b1)  bf16
    gemm_bt<2><<<dim3(32, 128), 256, 0, stream>>>(bufB, w1T, b1, nullptr, bufA, nullptr, 4096, 1024);
    // 8) out = h @ w2 + b2 + x  (fp32)
    gemm_bt<1><<<dim3(8, 128), 256, 0, stream>>>(bufA, w2T, b2, xbuf, nullptr, outp, 1024, 4096);
}

// Round 2
// 882.601 us; speedup vs baseline: 1.0446x; 1.0446x over previous
//
#include <hip/hip_runtime.h>
#include <hip/hip_bf16.h>
#include <math.h>

typedef __attribute__((ext_vector_type(8))) short short8;
typedef __attribute__((ext_vector_type(4))) float floatx4;

__device__ __forceinline__ float bf2f(unsigned int u) {
    union { unsigned int i; float f; } c; c.i = u << 16; return c.f;
}
__device__ __forceinline__ unsigned short f2bf(float f) {
    unsigned int x = __builtin_bit_cast(unsigned int, f);
    unsigned int r = (x + 0x7fffu + ((x >> 16) & 1u)) >> 16;
    return (unsigned short)r;
}
__device__ __forceinline__ float elu1(float x) { return x > 0.f ? x + 1.f : __expf(x); }
__device__ __forceinline__ float gelu_exact(float x) {
    return 0.5f * x * (1.f + erff(x * 0.70710678118654752f));
}

__device__ __forceinline__ void async_cp16(const void* g, void* l) {
    __builtin_amdgcn_global_load_lds(
        (const __attribute__((address_space(1))) unsigned int*)g,
        (__attribute__((address_space(3))) unsigned int*)l, 16, 0, 0);
}

// ---------------- prep: 4 weight transposes (fp32 [K,N] -> bf16 [N,K]) + kvz zero -------
// tile ranges: [0,3072) qkv_w, [3072,4096) out_w, [4096,8192) w1, [8192,12288) w2,
// [12288,12548) zero kvz (260 blocks x 1024 floats)
__global__ void prep_kernel(const float* __restrict__ qkv_w, const float* __restrict__ out_w,
                            const float* __restrict__ w1, const float* __restrict__ w2,
                            unsigned short* __restrict__ qkvwT, unsigned short* __restrict__ outwT,
                            unsigned short* __restrict__ w1T, unsigned short* __restrict__ w2T,
                            float* __restrict__ kvz) {
    const int bid = blockIdx.x;
    const int tx = threadIdx.x, ty = threadIdx.y;   // 32 x 8
    if (bid >= 12288) {
        const int lid = ty * 32 + tx;
        const int i = (bid - 12288) * 1024 + lid * 4;
        *(float4*)(kvz + i) = make_float4(0.f, 0.f, 0.f, 0.f);
        return;
    }
    const float* in;
    unsigned short* op;
    int K, N, tb;
    if (bid < 3072)      { in = qkv_w; op = qkvwT; K = 1024; N = 3072; tb = bid; }
    else if (bid < 4096) { in = out_w; op = outwT; K = 1024; N = 1024; tb = bid - 3072; }
    else if (bid < 8192) { in = w1;    op = w1T;   K = 1024; N = 4096; tb = bid - 4096; }
    else                 { in = w2;    op = w2T;   K = 4096; N = 1024; tb = bid - 8192; }
    const int nx = N >> 5;
    const int n0 = (tb % nx) * 32, k0 = (tb / nx) * 32;
    __shared__ float tile[32][33];
#pragma unroll
    for (int i = 0; i < 4; i++)
        tile[ty + 8 * i][tx] = in[(size_t)(k0 + ty + 8 * i) * N + n0 + tx];
    __syncthreads();
#pragma unroll
    for (int i = 0; i < 4; i++)
        op[(size_t)(n0 + ty + 8 * i) * K + k0 + tx] = f2bf(tile[tx][ty + 8 * i]);
}

// ---------------- LayerNorm: fp32 [M,1024] -> bf16 [M,1024] ----------------
__global__ __launch_bounds__(256)
void ln_kernel(const float* __restrict__ x, const float* __restrict__ g,
               const float* __restrict__ be, unsigned short* __restrict__ out) {
    const int row = blockIdx.x;
    const int t = threadIdx.x;
    const float4 v = *(const float4*)(x + (size_t)row * 1024 + t * 4);
    float s = v.x + v.y + v.z + v.w;
    float s2 = v.x * v.x + v.y * v.y + v.z * v.z + v.w * v.w;
#pragma unroll
    for (int off = 32; off > 0; off >>= 1) {
        s += __shfl_down(s, off);
        s2 += __shfl_down(s2, off);
    }
    __shared__ float red[8];
    __shared__ float stat[2];
    const int w = t >> 6, l = t & 63;
    if (l == 0) { red[w] = s; red[4 + w] = s2; }
    __syncthreads();
    if (t == 0) {
        float S = red[0] + red[1] + red[2] + red[3];
        float S2 = red[4] + red[5] + red[6] + red[7];
        float mu = S * (1.f / 1024.f);
        float var = S2 * (1.f / 1024.f) - mu * mu;
        stat[0] = mu;
        stat[1] = rsqrtf(var + 1e-5f);
    }
    __syncthreads();
    const float mu = stat[0], rs = stat[1];
    const float4 gv = *(const float4*)(g + t * 4);
    const float4 bv = *(const float4*)(be + t * 4);
    unsigned int o0 = f2bf((v.x - mu) * rs * gv.x + bv.x);
    unsigned int o1 = f2bf((v.y - mu) * rs * gv.y + bv.y);
    unsigned int o2 = f2bf((v.z - mu) * rs * gv.z + bv.z);
    unsigned int o3 = f2bf((v.w - mu) * rs * gv.w + bv.w);
    uint2 pk;
    pk.x = o0 | (o1 << 16);
    pk.y = o2 | (o3 << 16);
    *(uint2*)(out + (size_t)row * 1024 + t * 4) = pk;
}

// ---------------- GEMM: C[M,N] = A[M,K](bf16) * B[N,K](bf16)^T + bias, fused epilogue ----
// EPI 0: bias; cols<2048 get elu+1 (qkv feature map); store bf16
// EPI 1: bias + residual(fp32 [M,N]); store fp32
// EPI 2: bias + exact gelu; store bf16
template <int EPI>
__global__ __launch_bounds__(256, 4)
void gemm_bt(const unsigned short* __restrict__ A, const unsigned short* __restrict__ B,
             const float* __restrict__ bias, const float* __restrict__ resid,
             unsigned short* __restrict__ Cbf, float* __restrict__ Cf32,
             int N, int K) {
    __shared__ unsigned short At[128 * 32];
    __shared__ unsigned short Bt[128 * 32];
    const int t = threadIdx.x;
    const int l = t & 63;
    const int w = t >> 6;

    // XCD-aware swizzle: flat id f -> xcd = f%8 (round-robin dispatch); give each XCD a
    // contiguous strip of M-panels, iterating N fastest, so co-resident blocks on one XCD
    // share A-tiles in its private L2 instead of 8 XCDs each re-fetching the same panel.
    const int T = gridDim.x * gridDim.y;
    const int f = blockIdx.y * gridDim.x + blockIdx.x;
    int bx = blockIdx.x, by = blockIdx.y;
    if ((T & 7) == 0) {
        const int per = T >> 3;
        const int g = (f & 7) * per + (f >> 3);
        bx = g % gridDim.x;
        by = g / gridDim.x;
    }
    const int m0 = by * 128;
    const int n0 = bx * 128;
    const int wm = (w >> 1) * 64;
    const int wn = (w & 1) * 64;

    floatx4 acc[4][4];
    const floatx4 zz = {0.f, 0.f, 0.f, 0.f};
#pragma unroll
    for (int i = 0; i < 4; i++)
#pragma unroll
        for (int j = 0; j < 4; j++) acc[i][j] = zz;

    // staging: thread t covers LDS elems [t*8, t*8+8); row=t>>2, col=(t&3)*8
    const int sr = t >> 2;
    const int sc = (t & 3) << 3;
    const unsigned short* ag = A + (size_t)(m0 + sr) * K + sc;
    const unsigned short* ag2 = ag + (size_t)64 * K;
    const unsigned short* bg = B + (size_t)(n0 + sr) * K + sc;
    const unsigned short* bg2 = bg + (size_t)64 * K;
    unsigned short* la = At + t * 8;
    unsigned short* la2 = At + 2048 + t * 8;
    unsigned short* lb = Bt + t * 8;
    unsigned short* lb2 = Bt + 2048 + t * 8;

    const int fr = l & 15;
    const int fo = (l >> 4) << 3;

    for (int k0 = 0; k0 < K; k0 += 32) {
        async_cp16(ag + k0, la);
        async_cp16(ag2 + k0, la2);
        async_cp16(bg + k0, lb);
        async_cp16(bg2 + k0, lb2);
        __syncthreads();
        short8 af[4], bf[4];
#pragma unroll
        for (int i = 0; i < 4; i++)
            af[i] = *(const short8*)(At + (wm + i * 16 + fr) * 32 + fo);
#pragma unroll
        for (int i = 0; i < 4; i++)
            bf[i] = *(const short8*)(Bt + (wn + i * 16 + fr) * 32 + fo);
#pragma unroll
        for (int i = 0; i < 4; i++)
#pragma unroll
            for (int j = 0; j < 4; j++)
                acc[i][j] = __builtin_amdgcn_mfma_f32_16x16x32_bf16(af[i], bf[j], acc[i][j], 0, 0, 0);
        __syncthreads();
    }

    // epilogue: D[m][n] lane map: n = l&15, m = (l>>4)*4 + reg
    const int er = (l >> 4) << 2;
    const int ec = l & 15;
#pragma unroll
    for (int j = 0; j < 4; j++) {
        const int col = n0 + wn + j * 16 + ec;
        const float bb = bias[col];
#pragma unroll
        for (int i = 0; i < 4; i++) {
            const int rowb = m0 + wm + i * 16 + er;
#pragma unroll
            for (int r = 0; r < 4; r++) {
                const int row = rowb + r;
                float v = acc[i][j][r] + bb;
                const size_t idx = (size_t)row * N + col;
                if (EPI == 0) {
                    if (col < 2048) v = elu1(v);
                    Cbf[idx] = f2bf(v);
                } else if (EPI == 1) {
                    Cf32[idx] = v + resid[idx];
                } else {
                    Cbf[idx] = f2bf(gelu_exact(v));
                }
            }
        }
    }
}

// ---------------- kv[e][d] = sum_n kf[n][e] v[n][d]; z[e] = sum_n kf[n][e] ----------------
// qkv layout: [16384, 3072] bf16, q=0:1024 (elu'd), k=1024:2048 (elu'd), v=2048:3072
__global__ __launch_bounds__(256)
void kv_kernel(const unsigned short* __restrict__ qkv, float* __restrict__ kvz) {
    const int bh = blockIdx.x;     // 0..63
    const int chunk = blockIdx.y;  // 0..7, 512 tokens each
    const int b = bh >> 4, h = bh & 15;
    const int t = threadIdx.x;
    __shared__ float kf[64][68];
    __shared__ float vv[64][68];
    const int te = t >> 4, td = t & 15;
    float acc[4][4];
#pragma unroll
    for (int i = 0; i < 4; i++)
#pragma unroll
        for (int j = 0; j < 4; j++) acc[i][j] = 0.f;
    float zacc = 0.f;
    const size_t base = (size_t)b * 4096 * 3072 + (size_t)chunk * 512 * 3072;
    const int koff = 1024 + h * 64;
    const int voff = 2048 + h * 64;
    const int rl = t >> 3, seg = t & 7;

    for (int s = 0; s < 8; s++) {
#pragma unroll
        for (int p = 0; p < 2; p++) {
            const int nl = p * 32 + rl;
            const unsigned short* rp = qkv + base + (size_t)(s * 64 + nl) * 3072;
            const uint4 kd = *(const uint4*)(rp + koff + seg * 8);
            const uint4 vd = *(const uint4*)(rp + voff + seg * 8);
            float* kdst = &kf[nl][seg * 8];
            float* vdst = &vv[nl][seg * 8];
            kdst[0] = bf2f(kd.x & 0xffff); kdst[1] = bf2f(kd.x >> 16);
            kdst[2] = bf2f(kd.y & 0xffff); kdst[3] = bf2f(kd.y >> 16);
            kdst[4] = bf2f(kd.z & 0xffff); kdst[5] = bf2f(kd.z >> 16);
            kdst[6] = bf2f(kd.w & 0xffff); kdst[7] = bf2f(kd.w >> 16);
            vdst[0] = bf2f(vd.x & 0xffff); vdst[1] = bf2f(vd.x >> 16);
            vdst[2] = bf2f(vd.y & 0xffff); vdst[3] = bf2f(vd.y >> 16);
            vdst[4] = bf2f(vd.z & 0xffff); vdst[5] = bf2f(vd.z >> 16);
            vdst[6] = bf2f(vd.w & 0xffff); vdst[7] = bf2f(vd.w >> 16);
        }
        __syncthreads();
        for (int n = 0; n < 64; n++) {
            const float4 kk = *(const float4*)&kf[n][te * 4];
            const float4 vn = *(const float4*)&vv[n][td * 4];
            const float ka[4] = {kk.x, kk.y, kk.z, kk.w};
            const float va[4] = {vn.x, vn.y, vn.z, vn.w};
#pragma unroll
            for (int i = 0; i < 4; i++)
#pragma unroll
                for (int j = 0; j < 4; j++) acc[i][j] = fmaf(ka[i], va[j], acc[i][j]);
        }
        if (t < 64) {
            for (int n = 0; n < 64; n++) zacc += kf[n][t];
        }
        __syncthreads();
    }
    float* kvp = kvz + bh * 4160;
#pragma unroll
    for (int i = 0; i < 4; i++)
#pragma unroll
        for (int j = 0; j < 4; j++)
            atomicAdd(&kvp[(te * 4 + i) * 64 + td * 4 + j], acc[i][j]);
    if (t < 64) atomicAdd(&kvp[4096 + t], zacc);
}

// ---------------- y[n][d] = (sum_e qf[n][e] kv[e][d]) / max(qf.z, eps), store bf16 -------
__global__ __launch_bounds__(256)
void y_kernel(const unsigned short* __restrict__ qkv, const float* __restrict__ kvz,
              unsigned short* __restrict__ y) {
    const int bh = blockIdx.x, chunk = blockIdx.y;  // 64 x 32 (128 tokens/chunk)
    const int b = bh >> 4, h = bh & 15;
    const int t = threadIdx.x;
    __shared__ float kv[64][68];
    __shared__ float zs[64];
    __shared__ float qf[16][68];
    const float* kvp = kvz + bh * 4160;
#pragma unroll
    for (int p = 0; p < 4; p++) {
        const int f = (t + p * 256) * 4;
        const float4 v4 = *(const float4*)(kvp + f);
        *(float4*)&kv[f >> 6][f & 63] = v4;
    }
    if (t < 16) *(float4*)&zs[t * 4] = *(const float4*)(kvp + 4096 + t * 4);
    __syncthreads();
    const int nl = t >> 4, td = t & 15;
    const size_t base = (size_t)b * 4096 * 3072 + (size_t)chunk * 128 * 3072;
    const int qoff = h * 64;
    for (int s = 0; s < 8; s++) {
        if (t < 128) {
            const int r = t >> 3, seg = t & 7;
            const uint4 qd = *(const uint4*)(qkv + base + (size_t)(s * 16 + r) * 3072 + qoff + seg * 8);
            float* qdst = &qf[r][seg * 8];
            qdst[0] = bf2f(qd.x & 0xffff); qdst[1] = bf2f(qd.x >> 16);
            qdst[2] = bf2f(qd.y & 0xffff); qdst[3] = bf2f(qd.y >> 16);
            qdst[4] = bf2f(qd.z & 0xffff); qdst[5] = bf2f(qd.z >> 16);
            qdst[6] = bf2f(qd.w & 0xffff); qdst[7] = bf2f(qd.w >> 16);
        }
        __syncthreads();
        float a0 = 0.f, a1 = 0.f, a2 = 0.f, a3 = 0.f, den = 0.f;
        for (int e = 0; e < 64; e++) {
            const float q = qf[nl][e];
            const float4 kvv = *(const float4*)&kv[e][td * 4];
            a0 = fmaf(q, kvv.x, a0);
            a1 = fmaf(q, kvv.y, a1);
            a2 = fmaf(q, kvv.z, a2);
            a3 = fmaf(q, kvv.w, a3);
            den = fmaf(q, zs[e], den);
        }
        const float inv = 1.f / fmaxf(den, 1e-6f);
        const int tok = b * 4096 + chunk * 128 + s * 16 + nl;
        unsigned int o0 = f2bf(a0 * inv), o1 = f2bf(a1 * inv);
        unsigned int o2 = f2bf(a2 * inv), o3 = f2bf(a3 * inv);
        uint2 pk;
        pk.x = o0 | (o1 << 16);
        pk.y = o2 | (o3 << 16);
        *(uint2*)(y + (size_t)tok * 1024 + h * 64 + td * 4) = pk;
        __syncthreads();
    }
}

extern "C" void kernel_launch(void* const* d_in, const int* in_sizes, int n_in,
                              void* d_out, int out_size, void* d_ws, size_t ws_size,
                              hipStream_t stream) {
    const float* src   = (const float*)d_in[0];
    const float* qkv_w = (const float*)d_in[1];
    const float* qkv_b = (const float*)d_in[2];
    const float* out_w = (const float*)d_in[3];
    const float* out_b = (const float*)d_in[4];
    const float* w1    = (const float*)d_in[5];
    const float* b1    = (const float*)d_in[6];
    const float* w2    = (const float*)d_in[7];
    const float* b2    = (const float*)d_in[8];
    const float* g1    = (const float*)d_in[9];
    const float* be1   = (const float*)d_in[10];
    const float* g2    = (const float*)d_in[11];
    const float* be2   = (const float*)d_in[12];
    float* outp = (float*)d_out;

    char* ws = (char*)d_ws;
    unsigned short* qkvwT = (unsigned short*)(ws + 0);          // 3072x1024 bf16
    unsigned short* outwT = (unsigned short*)(ws + 6291456);    // 1024x1024 bf16
    unsigned short* w1T   = (unsigned short*)(ws + 8388608);    // 4096x1024 bf16
    unsigned short* w2T   = (unsigned short*)(ws + 16777216);   // 1024x4096 bf16
    unsigned short* bufA  = (unsigned short*)(ws + 25165824);   // qkv [16384,3072] then h [16384,4096] bf16
    unsigned short* bufB  = (unsigned short*)(ws + 159383552);  // ln1 -> y -> ln2 [16384,1024] bf16
    float*          xbuf  = (float*)(ws + 192937984);           // x [16384,1024] fp32
    float*          kvz   = (float*)(ws + 260046848);           // 64*(64*64+64) fp32

    // weights -> bf16 transposed [N,K]; kvz zeroed; one launch
    prep_kernel<<<12548, dim3(32, 8), 0, stream>>>(qkv_w, out_w, w1, w2,
                                                   qkvwT, outwT, w1T, w2T, kvz);

    // 1) ln1 = LN(src)
    ln_kernel<<<16384, 256, 0, stream>>>(src, g1, be1, bufB);
    // 2) qkv = ln1 @ qkv_w + b (elu+1 fused on q,k cols), bf16
    gemm_bt<0><<<dim3(24, 128), 256, 0, stream>>>(bufB, qkvwT, qkv_b, nullptr, bufA, nullptr, 3072, 1024);
    // 3) kv, z aggregation
    kv_kernel<<<dim3(64, 8), 256, 0, stream>>>(bufA, kvz);
    // 4) y = qf@kv / den  (bf16, [16384,1024] in [b,n,h,d] order)
    y_kernel<<<dim3(64, 32), 256, 0, stream>>>(bufA, kvz, bufB);
    // 5) x = y @ out_w + out_b + src  (fp32)
    gemm_bt<1><<<dim3(8, 128), 256, 0, stream>>>(bufB, outwT, out_b, src, nullptr, xbuf, 1024, 1024);
    // 6) ln2 = LN(x)
    ln_kernel<<<16384, 256, 0, stream>>>(xbuf, g2, be2, bufB);
    // 7) h = gelu(ln2 @ w1 + b1)  bf16
    gemm_bt<2><<<dim3(32, 128), 256, 0, stream>>>(bufB, w1T, b1, nullptr, bufA, nullptr, 4096, 1024);
    // 8) out = h @ w2 + b2 + x  (fp32)
    gemm_bt<1><<<dim3(8, 128), 256, 0, stream>>>(bufA, w2T, b2, xbuf, nullptr, outp, 1024, 4096);
}

// Round 3
// 846.989 us; speedup vs baseline: 1.0885x; 1.0420x over previous
//
#include <hip/hip_runtime.h>
#include <hip/hip_bf16.h>
#include <math.h>

typedef __attribute__((ext_vector_type(8))) short short8;
typedef __attribute__((ext_vector_type(4))) float floatx4;

__device__ __forceinline__ float bf2f(unsigned int u) {
    union { unsigned int i; float f; } c; c.i = u << 16; return c.f;
}
__device__ __forceinline__ unsigned short f2bf(float f) {
    unsigned int x = __builtin_bit_cast(unsigned int, f);
    unsigned int r = (x + 0x7fffu + ((x >> 16) & 1u)) >> 16;
    return (unsigned short)r;
}
__device__ __forceinline__ float elu1(float x) { return x > 0.f ? x + 1.f : __expf(x); }
// tanh-form GELU: 0.5x(1+tanh(0.79788456(x+0.044715x^3))) = x*sigmoid(1.59576912*u)
// max |dev| from exact-erf gelu ~3e-4 — far below bf16 rounding already present.
__device__ __forceinline__ float gelu_fast(float x) {
    float u = x * (1.f + 0.044715f * x * x);
    return x / (1.f + __expf(-1.5957691216f * u));
}

__device__ __forceinline__ void async_cp16(const void* g, void* l) {
    __builtin_amdgcn_global_load_lds(
        (const __attribute__((address_space(1))) unsigned int*)g,
        (__attribute__((address_space(3))) unsigned int*)l, 16, 0, 0);
}

// ---------------- prep: 4 weight transposes (fp32 [K,N] -> bf16 [N,K]) + kvz zero -------
__global__ void prep_kernel(const float* __restrict__ qkv_w, const float* __restrict__ out_w,
                            const float* __restrict__ w1, const float* __restrict__ w2,
                            unsigned short* __restrict__ qkvwT, unsigned short* __restrict__ outwT,
                            unsigned short* __restrict__ w1T, unsigned short* __restrict__ w2T,
                            float* __restrict__ kvz) {
    const int bid = blockIdx.x;
    const int tx = threadIdx.x, ty = threadIdx.y;   // 32 x 8
    if (bid >= 12288) {
        const int lid = ty * 32 + tx;
        const int i = (bid - 12288) * 1024 + lid * 4;
        *(float4*)(kvz + i) = make_float4(0.f, 0.f, 0.f, 0.f);
        return;
    }
    const float* in;
    unsigned short* op;
    int K, N, tb;
    if (bid < 3072)      { in = qkv_w; op = qkvwT; K = 1024; N = 3072; tb = bid; }
    else if (bid < 4096) { in = out_w; op = outwT; K = 1024; N = 1024; tb = bid - 3072; }
    else if (bid < 8192) { in = w1;    op = w1T;   K = 1024; N = 4096; tb = bid - 4096; }
    else                 { in = w2;    op = w2T;   K = 4096; N = 1024; tb = bid - 8192; }
    const int nx = N >> 5;
    const int n0 = (tb % nx) * 32, k0 = (tb / nx) * 32;
    __shared__ float tile[32][33];
#pragma unroll
    for (int i = 0; i < 4; i++)
        tile[ty + 8 * i][tx] = in[(size_t)(k0 + ty + 8 * i) * N + n0 + tx];
    __syncthreads();
#pragma unroll
    for (int i = 0; i < 4; i++)
        op[(size_t)(n0 + ty + 8 * i) * K + k0 + tx] = f2bf(tile[tx][ty + 8 * i]);
}

// ---------------- LayerNorm: fp32 or bf16 input [M,1024] -> bf16 [M,1024] ----------------
template <int IN_BF16>
__global__ __launch_bounds__(256)
void ln_kernel(const void* __restrict__ xv, const float* __restrict__ g,
               const float* __restrict__ be, unsigned short* __restrict__ out) {
    const int row = blockIdx.x;
    const int t = threadIdx.x;
    float4 v;
    if (IN_BF16) {
        const unsigned short* x = (const unsigned short*)xv;
        uint2 r = *(const uint2*)(x + (size_t)row * 1024 + t * 4);
        v.x = bf2f(r.x & 0xffff); v.y = bf2f(r.x >> 16);
        v.z = bf2f(r.y & 0xffff); v.w = bf2f(r.y >> 16);
    } else {
        v = *(const float4*)((const float*)xv + (size_t)row * 1024 + t * 4);
    }
    float s = v.x + v.y + v.z + v.w;
    float s2 = v.x * v.x + v.y * v.y + v.z * v.z + v.w * v.w;
#pragma unroll
    for (int off = 32; off > 0; off >>= 1) {
        s += __shfl_down(s, off);
        s2 += __shfl_down(s2, off);
    }
    __shared__ float red[8];
    __shared__ float stat[2];
    const int w = t >> 6, l = t & 63;
    if (l == 0) { red[w] = s; red[4 + w] = s2; }
    __syncthreads();
    if (t == 0) {
        float S = red[0] + red[1] + red[2] + red[3];
        float S2 = red[4] + red[5] + red[6] + red[7];
        float mu = S * (1.f / 1024.f);
        float var = S2 * (1.f / 1024.f) - mu * mu;
        stat[0] = mu;
        stat[1] = rsqrtf(var + 1e-5f);
    }
    __syncthreads();
    const float mu = stat[0], rs = stat[1];
    const float4 gv = *(const float4*)(g + t * 4);
    const float4 bv = *(const float4*)(be + t * 4);
    unsigned int o0 = f2bf((v.x - mu) * rs * gv.x + bv.x);
    unsigned int o1 = f2bf((v.y - mu) * rs * gv.y + bv.y);
    unsigned int o2 = f2bf((v.z - mu) * rs * gv.z + bv.z);
    unsigned int o3 = f2bf((v.w - mu) * rs * gv.w + bv.w);
    uint2 pk;
    pk.x = o0 | (o1 << 16);
    pk.y = o2 | (o3 << 16);
    *(uint2*)(out + (size_t)row * 1024 + t * 4) = pk;
}

// ---------------- GEMM: C[M,N] = A[M,K](bf16) * B[N,K](bf16)^T + bias, fused epilogue ----
// EPI 0: bias; cols<2048 get elu+1 (qkv feature map); store bf16
// EPI 2: bias + gelu; store bf16
// EPI 3: bias + resid fp32; store bf16
// EPI 4: bias + resid bf16; store fp32
template <int EPI>
__global__ __launch_bounds__(256, 4)
void gemm_bt(const unsigned short* __restrict__ A, const unsigned short* __restrict__ B,
             const float* __restrict__ bias, const float* __restrict__ resid,
             const unsigned short* __restrict__ residb,
             unsigned short* __restrict__ Cbf, float* __restrict__ Cf32,
             int N, int K) {
    __shared__ unsigned short At[128 * 32];
    __shared__ unsigned short Bt[128 * 32];
    const int t = threadIdx.x;
    const int l = t & 63;
    const int w = t >> 6;

    // XCD-aware swizzle: each XCD gets a contiguous strip of M-panels, N iterating fastest,
    // so co-resident blocks on one XCD share A-tiles in its private L2.
    const int T = gridDim.x * gridDim.y;
    const int f = blockIdx.y * gridDim.x + blockIdx.x;
    int bx = blockIdx.x, by = blockIdx.y;
    if ((T & 7) == 0) {
        const int per = T >> 3;
        const int g = (f & 7) * per + (f >> 3);
        bx = g % gridDim.x;
        by = g / gridDim.x;
    }
    const int m0 = by * 128;
    const int n0 = bx * 128;
    const int wm = (w >> 1) * 64;
    const int wn = (w & 1) * 64;

    floatx4 acc[4][4];
    const floatx4 zz = {0.f, 0.f, 0.f, 0.f};
#pragma unroll
    for (int i = 0; i < 4; i++)
#pragma unroll
        for (int j = 0; j < 4; j++) acc[i][j] = zz;

    // Staging with XOR bank-swizzle. Lane t's LDS slot is fixed (base + t*16B, required by
    // global_load_lds); we permute which GLOBAL 16B granule it fetches:
    //   logical (row R, granule c) lives at phys granule R*4 + (c ^ ((R>>1)&3)).
    // Lane t holds phys granule t (row t>>2), so it fetches c_log = (t&3) ^ ((t>>3)&3).
    const int sr = t >> 2;
    const int sc = (((t & 3) ^ ((t >> 3) & 3)) << 3);
    const unsigned short* ag = A + (size_t)(m0 + sr) * K + sc;
    const unsigned short* ag2 = ag + (size_t)64 * K;
    const unsigned short* bg = B + (size_t)(n0 + sr) * K + sc;
    const unsigned short* bg2 = bg + (size_t)64 * K;
    unsigned short* la = At + t * 8;
    unsigned short* la2 = At + 2048 + t * 8;
    unsigned short* lb = Bt + t * 8;
    unsigned short* lb2 = Bt + 2048 + t * 8;

    // Fragment read: logical (row = wm+i*16+fr, granule g=l>>4) -> phys granule offset
    // g ^ ((row>>1)&3) = g ^ ((l>>1)&3)  (wm, i*16 are ≡0 mod 8 after >>1&3).
    // Bank spread: 16 lanes/granule-group cover all 32 banks 2-way -> conflict-free.
    const int fr = l & 15;
    const int fo = (((l >> 4) ^ ((l >> 1) & 3)) << 3);

    for (int k0 = 0; k0 < K; k0 += 32) {
        async_cp16(ag + k0, la);
        async_cp16(ag2 + k0, la2);
        async_cp16(bg + k0, lb);
        async_cp16(bg2 + k0, lb2);
        __syncthreads();
        short8 af[4], bf[4];
#pragma unroll
        for (int i = 0; i < 4; i++)
            af[i] = *(const short8*)(At + (wm + i * 16 + fr) * 32 + fo);
#pragma unroll
        for (int i = 0; i < 4; i++)
            bf[i] = *(const short8*)(Bt + (wn + i * 16 + fr) * 32 + fo);
#pragma unroll
        for (int i = 0; i < 4; i++)
#pragma unroll
            for (int j = 0; j < 4; j++)
                acc[i][j] = __builtin_amdgcn_mfma_f32_16x16x32_bf16(af[i], bf[j], acc[i][j], 0, 0, 0);
        __syncthreads();
    }

    // epilogue: D[m][n] lane map: n = l&15, m = (l>>4)*4 + reg
    const int er = (l >> 4) << 2;
    const int ec = l & 15;
#pragma unroll
    for (int j = 0; j < 4; j++) {
        const int col = n0 + wn + j * 16 + ec;
        const float bb = bias[col];
#pragma unroll
        for (int i = 0; i < 4; i++) {
            const int rowb = m0 + wm + i * 16 + er;
#pragma unroll
            for (int r = 0; r < 4; r++) {
                const int row = rowb + r;
                float v = acc[i][j][r] + bb;
                const size_t idx = (size_t)row * N + col;
                if (EPI == 0) {
                    if (col < 2048) v = elu1(v);
                    Cbf[idx] = f2bf(v);
                } else if (EPI == 2) {
                    Cbf[idx] = f2bf(gelu_fast(v));
                } else if (EPI == 3) {
                    Cbf[idx] = f2bf(v + resid[idx]);
                } else {
                    Cf32[idx] = v + bf2f(residb[idx]);
                }
            }
        }
    }
}

// ---------------- kv[e][d] = sum_n kf[n][e] v[n][d]; z[e] = sum_n kf[n][e] ----------------
__global__ __launch_bounds__(256)
void kv_kernel(const unsigned short* __restrict__ qkv, float* __restrict__ kvz) {
    const int bh = blockIdx.x;     // 0..63
    const int chunk = blockIdx.y;  // 0..7, 512 tokens each
    const int b = bh >> 4, h = bh & 15;
    const int t = threadIdx.x;
    __shared__ float kf[64][68];
    __shared__ float vv[64][68];
    const int te = t >> 4, td = t & 15;
    float acc[4][4];
#pragma unroll
    for (int i = 0; i < 4; i++)
#pragma unroll
        for (int j = 0; j < 4; j++) acc[i][j] = 0.f;
    float zacc = 0.f;
    const size_t base = (size_t)b * 4096 * 3072 + (size_t)chunk * 512 * 3072;
    const int koff = 1024 + h * 64;
    const int voff = 2048 + h * 64;
    const int rl = t >> 3, seg = t & 7;

    for (int s = 0; s < 8; s++) {
#pragma unroll
        for (int p = 0; p < 2; p++) {
            const int nl = p * 32 + rl;
            const unsigned short* rp = qkv + base + (size_t)(s * 64 + nl) * 3072;
            const uint4 kd = *(const uint4*)(rp + koff + seg * 8);
            const uint4 vd = *(const uint4*)(rp + voff + seg * 8);
            float* kdst = &kf[nl][seg * 8];
            float* vdst = &vv[nl][seg * 8];
            kdst[0] = bf2f(kd.x & 0xffff); kdst[1] = bf2f(kd.x >> 16);
            kdst[2] = bf2f(kd.y & 0xffff); kdst[3] = bf2f(kd.y >> 16);
            kdst[4] = bf2f(kd.z & 0xffff); kdst[5] = bf2f(kd.z >> 16);
            kdst[6] = bf2f(kd.w & 0xffff); kdst[7] = bf2f(kd.w >> 16);
            vdst[0] = bf2f(vd.x & 0xffff); vdst[1] = bf2f(vd.x >> 16);
            vdst[2] = bf2f(vd.y & 0xffff); vdst[3] = bf2f(vd.y >> 16);
            vdst[4] = bf2f(vd.z & 0xffff); vdst[5] = bf2f(vd.z >> 16);
            vdst[6] = bf2f(vd.w & 0xffff); vdst[7] = bf2f(vd.w >> 16);
        }
        __syncthreads();
        for (int n = 0; n < 64; n++) {
            const float4 kk = *(const float4*)&kf[n][te * 4];
            const float4 vn = *(const float4*)&vv[n][td * 4];
            const float ka[4] = {kk.x, kk.y, kk.z, kk.w};
            const float va[4] = {vn.x, vn.y, vn.z, vn.w};
#pragma unroll
            for (int i = 0; i < 4; i++)
#pragma unroll
                for (int j = 0; j < 4; j++) acc[i][j] = fmaf(ka[i], va[j], acc[i][j]);
        }
        if (t < 64) {
            for (int n = 0; n < 64; n++) zacc += kf[n][t];
        }
        __syncthreads();
    }
    float* kvp = kvz + bh * 4160;
#pragma unroll
    for (int i = 0; i < 4; i++)
#pragma unroll
        for (int j = 0; j < 4; j++)
            atomicAdd(&kvp[(te * 4 + i) * 64 + td * 4 + j], acc[i][j]);
    if (t < 64) atomicAdd(&kvp[4096 + t], zacc);
}

// ---------------- y[n][d] = (sum_e qf[n][e] kv[e][d]) / max(den, eps), store bf16 -------
__global__ __launch_bounds__(256)
void y_kernel(const unsigned short* __restrict__ qkv, const float* __restrict__ kvz,
              unsigned short* __restrict__ y) {
    const int bh = blockIdx.x, chunk = blockIdx.y;  // 64 x 32 (128 tokens/chunk)
    const int b = bh >> 4, h = bh & 15;
    const int t = threadIdx.x;
    __shared__ float kv[64][68];
    __shared__ float zs[64];
    __shared__ float qf[16][68];
    const float* kvp = kvz + bh * 4160;
#pragma unroll
    for (int p = 0; p < 4; p++) {
        const int f = (t + p * 256) * 4;
        const float4 v4 = *(const float4*)(kvp + f);
        *(float4*)&kv[f >> 6][f & 63] = v4;
    }
    if (t < 16) *(float4*)&zs[t * 4] = *(const float4*)(kvp + 4096 + t * 4);
    __syncthreads();
    const int nl = t >> 4, td = t & 15;
    const size_t base = (size_t)b * 4096 * 3072 + (size_t)chunk * 128 * 3072;
    const int qoff = h * 64;
    for (int s = 0; s < 8; s++) {
        if (t < 128) {
            const int r = t >> 3, seg = t & 7;
            const uint4 qd = *(const uint4*)(qkv + base + (size_t)(s * 16 + r) * 3072 + qoff + seg * 8);
            float* qdst = &qf[r][seg * 8];
            qdst[0] = bf2f(qd.x & 0xffff); qdst[1] = bf2f(qd.x >> 16);
            qdst[2] = bf2f(qd.y & 0xffff); qdst[3] = bf2f(qd.y >> 16);
            qdst[4] = bf2f(qd.z & 0xffff); qdst[5] = bf2f(qd.z >> 16);
            qdst[6] = bf2f(qd.w & 0xffff); qdst[7] = bf2f(qd.w >> 16);
        }
        __syncthreads();
        float a0 = 0.f, a1 = 0.f, a2 = 0.f, a3 = 0.f, den = 0.f;
        for (int e = 0; e < 64; e++) {
            const float q = qf[nl][e];
            const float4 kvv = *(const float4*)&kv[e][td * 4];
            a0 = fmaf(q, kvv.x, a0);
            a1 = fmaf(q, kvv.y, a1);
            a2 = fmaf(q, kvv.z, a2);
            a3 = fmaf(q, kvv.w, a3);
            den = fmaf(q, zs[e], den);
        }
        const float inv = 1.f / fmaxf(den, 1e-6f);
        const int tok = b * 4096 + chunk * 128 + s * 16 + nl;
        unsigned int o0 = f2bf(a0 * inv), o1 = f2bf(a1 * inv);
        unsigned int o2 = f2bf(a2 * inv), o3 = f2bf(a3 * inv);
        uint2 pk;
        pk.x = o0 | (o1 << 16);
        pk.y = o2 | (o3 << 16);
        *(uint2*)(y + (size_t)tok * 1024 + h * 64 + td * 4) = pk;
        __syncthreads();
    }
}

extern "C" void kernel_launch(void* const* d_in, const int* in_sizes, int n_in,
                              void* d_out, int out_size, void* d_ws, size_t ws_size,
                              hipStream_t stream) {
    const float* src   = (const float*)d_in[0];
    const float* qkv_w = (const float*)d_in[1];
    const float* qkv_b = (const float*)d_in[2];
    const float* out_w = (const float*)d_in[3];
    const float* out_b = (const float*)d_in[4];
    const float* w1    = (const float*)d_in[5];
    const float* b1    = (const float*)d_in[6];
    const float* w2    = (const float*)d_in[7];
    const float* b2    = (const float*)d_in[8];
    const float* g1    = (const float*)d_in[9];
    const float* be1   = (const float*)d_in[10];
    const float* g2    = (const float*)d_in[11];
    const float* be2   = (const float*)d_in[12];
    float* outp = (float*)d_out;

    char* ws = (char*)d_ws;
    unsigned short* qkvwT = (unsigned short*)(ws + 0);          // 3072x1024 bf16
    unsigned short* outwT = (unsigned short*)(ws + 6291456);    // 1024x1024 bf16
    unsigned short* w1T   = (unsigned short*)(ws + 8388608);    // 4096x1024 bf16
    unsigned short* w2T   = (unsigned short*)(ws + 16777216);   // 1024x4096 bf16
    unsigned short* bufA  = (unsigned short*)(ws + 25165824);   // qkv [16384,3072] / h [16384,4096] bf16
    unsigned short* bufB  = (unsigned short*)(ws + 159383552);  // ln1 -> y -> ln2 [16384,1024] bf16
    unsigned short* xbuf  = (unsigned short*)(ws + 192937984);  // x [16384,1024] bf16
    float*          kvz   = (float*)(ws + 260046848);           // 64*(64*64+64) fp32

    prep_kernel<<<12548, dim3(32, 8), 0, stream>>>(qkv_w, out_w, w1, w2,
                                                   qkvwT, outwT, w1T, w2T, kvz);

    // 1) ln1 = LN(src)  (fp32 in)
    ln_kernel<0><<<16384, 256, 0, stream>>>(src, g1, be1, bufB);
    // 2) qkv = ln1 @ qkv_w + b (elu+1 fused on q,k cols), bf16
    gemm_bt<0><<<dim3(24, 128), 256, 0, stream>>>(bufB, qkvwT, qkv_b, nullptr, nullptr, bufA, nullptr, 3072, 1024);
    // 3) kv, z aggregation
    kv_kernel<<<dim3(64, 8), 256, 0, stream>>>(bufA, kvz);
    // 4) y = qf@kv / den  (bf16)
    y_kernel<<<dim3(64, 32), 256, 0, stream>>>(bufA, kvz, bufB);
    // 5) x = y @ out_w + out_b + src  -> bf16 xbuf
    gemm_bt<3><<<dim3(8, 128), 256, 0, stream>>>(bufB, outwT, out_b, src, nullptr, xbuf, nullptr, 1024, 1024);
    // 6) ln2 = LN(x)  (bf16 in)
    ln_kernel<1><<<16384, 256, 0, stream>>>(xbuf, g2, be2, bufB);
    // 7) h = gelu(ln2 @ w1 + b1)  bf16
    gemm_bt<2><<<dim3(32, 128), 256, 0, stream>>>(bufB, w1T, b1, nullptr, nullptr, bufA, nullptr, 4096, 1024);
    // 8) out = h @ w2 + b2 + x  (fp32 out, bf16 resid)
    gemm_bt<4><<<dim3(8, 128), 256, 0, stream>>>(bufA, w2T, b2, nullptr, xbuf, nullptr, outp, 1024, 4096);
}

// Round 4
// 779.902 us; speedup vs baseline: 1.1821x; 1.0860x over previous
//
#include <hip/hip_runtime.h>
#include <hip/hip_bf16.h>
#include <math.h>

typedef __attribute__((ext_vector_type(8))) short short8;
typedef __attribute__((ext_vector_type(4))) float floatx4;

__device__ __forceinline__ float bf2f(unsigned int u) {
    union { unsigned int i; float f; } c; c.i = u << 16; return c.f;
}
__device__ __forceinline__ unsigned short f2bf(float f) {
    unsigned int x = __builtin_bit_cast(unsigned int, f);
    unsigned int r = (x + 0x7fffu + ((x >> 16) & 1u)) >> 16;
    return (unsigned short)r;
}
__device__ __forceinline__ float elu1(float x) { return x > 0.f ? x + 1.f : __expf(x); }
// tanh-form GELU (max |dev| ~3e-4 from exact erf — below bf16 rounding).
__device__ __forceinline__ float gelu_fast(float x) {
    float u = x * (1.f + 0.044715f * x * x);
    return x / (1.f + __expf(-1.5957691216f * u));
}

__device__ __forceinline__ void async_cp16(const void* g, void* l) {
    __builtin_amdgcn_global_load_lds(
        (const __attribute__((address_space(1))) unsigned int*)g,
        (__attribute__((address_space(3))) unsigned int*)l, 16, 0, 0);
}

// ---------------- prep: 4 weight transposes (fp32 [K,N] -> bf16 [N,K]) + kvz zero -------
__global__ void prep_kernel(const float* __restrict__ qkv_w, const float* __restrict__ out_w,
                            const float* __restrict__ w1, const float* __restrict__ w2,
                            unsigned short* __restrict__ qkvwT, unsigned short* __restrict__ outwT,
                            unsigned short* __restrict__ w1T, unsigned short* __restrict__ w2T,
                            float* __restrict__ kvz) {
    const int bid = blockIdx.x;
    const int tx = threadIdx.x, ty = threadIdx.y;   // 32 x 8
    if (bid >= 12288) {
        const int lid = ty * 32 + tx;
        const int i = (bid - 12288) * 1024 + lid * 4;
        *(float4*)(kvz + i) = make_float4(0.f, 0.f, 0.f, 0.f);
        return;
    }
    const float* in;
    unsigned short* op;
    int K, N, tb;
    if (bid < 3072)      { in = qkv_w; op = qkvwT; K = 1024; N = 3072; tb = bid; }
    else if (bid < 4096) { in = out_w; op = outwT; K = 1024; N = 1024; tb = bid - 3072; }
    else if (bid < 8192) { in = w1;    op = w1T;   K = 1024; N = 4096; tb = bid - 4096; }
    else                 { in = w2;    op = w2T;   K = 4096; N = 1024; tb = bid - 8192; }
    const int nx = N >> 5;
    const int n0 = (tb % nx) * 32, k0 = (tb / nx) * 32;
    __shared__ float tile[32][33];
#pragma unroll
    for (int i = 0; i < 4; i++)
        tile[ty + 8 * i][tx] = in[(size_t)(k0 + ty + 8 * i) * N + n0 + tx];
    __syncthreads();
#pragma unroll
    for (int i = 0; i < 4; i++)
        op[(size_t)(n0 + ty + 8 * i) * K + k0 + tx] = f2bf(tile[tx][ty + 8 * i]);
}

// ---------------- LayerNorm: fp32 or bf16 input [M,1024] -> bf16 [M,1024] ----------------
template <int IN_BF16>
__global__ __launch_bounds__(256)
void ln_kernel(const void* __restrict__ xv, const float* __restrict__ g,
               const float* __restrict__ be, unsigned short* __restrict__ out) {
    const int row = blockIdx.x;
    const int t = threadIdx.x;
    float4 v;
    if (IN_BF16) {
        const unsigned short* x = (const unsigned short*)xv;
        uint2 r = *(const uint2*)(x + (size_t)row * 1024 + t * 4);
        v.x = bf2f(r.x & 0xffff); v.y = bf2f(r.x >> 16);
        v.z = bf2f(r.y & 0xffff); v.w = bf2f(r.y >> 16);
    } else {
        v = *(const float4*)((const float*)xv + (size_t)row * 1024 + t * 4);
    }
    float s = v.x + v.y + v.z + v.w;
    float s2 = v.x * v.x + v.y * v.y + v.z * v.z + v.w * v.w;
#pragma unroll
    for (int off = 32; off > 0; off >>= 1) {
        s += __shfl_down(s, off);
        s2 += __shfl_down(s2, off);
    }
    __shared__ float red[8];
    __shared__ float stat[2];
    const int w = t >> 6, l = t & 63;
    if (l == 0) { red[w] = s; red[4 + w] = s2; }
    __syncthreads();
    if (t == 0) {
        float S = red[0] + red[1] + red[2] + red[3];
        float S2 = red[4] + red[5] + red[6] + red[7];
        float mu = S * (1.f / 1024.f);
        float var = S2 * (1.f / 1024.f) - mu * mu;
        stat[0] = mu;
        stat[1] = rsqrtf(var + 1e-5f);
    }
    __syncthreads();
    const float mu = stat[0], rs = stat[1];
    const float4 gv = *(const float4*)(g + t * 4);
    const float4 bv = *(const float4*)(be + t * 4);
    unsigned int o0 = f2bf((v.x - mu) * rs * gv.x + bv.x);
    unsigned int o1 = f2bf((v.y - mu) * rs * gv.y + bv.y);
    unsigned int o2 = f2bf((v.z - mu) * rs * gv.z + bv.z);
    unsigned int o3 = f2bf((v.w - mu) * rs * gv.w + bv.w);
    uint2 pk;
    pk.x = o0 | (o1 << 16);
    pk.y = o2 | (o3 << 16);
    *(uint2*)(out + (size_t)row * 1024 + t * 4) = pk;
}

// ---------------- GEMM: C[M,N] = A[M,K](bf16) * B[N,K](bf16)^T + bias, fused epilogue ----
// BK=64: LDS tiles 128x64 (16 KB each), 32 MFMA per barrier pair.
// EPI 0: bias; cols<2048 get elu+1; store bf16
// EPI 2: bias + gelu; store bf16
// EPI 3: bias + resid fp32; store bf16
// EPI 4: bias + resid bf16; store fp32
template <int EPI>
__global__ __launch_bounds__(256, 4)
void gemm_bt(const unsigned short* __restrict__ A, const unsigned short* __restrict__ B,
             const float* __restrict__ bias, const float* __restrict__ resid,
             const unsigned short* __restrict__ residb,
             unsigned short* __restrict__ Cbf, float* __restrict__ Cf32,
             int N, int K) {
    __shared__ unsigned short At[128 * 64];
    __shared__ unsigned short Bt[128 * 64];
    const int t = threadIdx.x;
    const int l = t & 63;
    const int w = t >> 6;

    // Two-level XCD-aware swizzle: xcd = f&7 owns a contiguous 16-row M-strip; within the
    // strip, N moves in chunks of 4 blocks (B-chunk L2-resident) with M fastest inside.
    const int f = blockIdx.y * gridDim.x + blockIdx.x;
    int bx = blockIdx.x, by = blockIdx.y;
    if (gridDim.y == 128 && (gridDim.x & 3) == 0) {
        const int xcd = f & 7;
        const int g = f >> 3;                  // [0, 16*gx)
        const int nin = g & 3;
        const int r = (g >> 2) & 15;
        const int nchunk = g >> 6;
        bx = nchunk * 4 + nin;
        by = xcd * 16 + r;
    }
    const int m0 = by * 128;
    const int n0 = bx * 128;
    const int wm = (w >> 1) * 64;
    const int wn = (w & 1) * 64;

    floatx4 acc[4][4];
    const floatx4 zz = {0.f, 0.f, 0.f, 0.f};
#pragma unroll
    for (int i = 0; i < 4; i++)
#pragma unroll
        for (int j = 0; j < 4; j++) acc[i][j] = zz;

    // Staging (BK=64): tile row stride = 64 elems (128 B = all 32 banks). Chunk c
    // (c=0..3) = rows [c*32, c*32+32). Thread t's fixed LDS slot: chunk base + t*16B,
    // i.e. phys granule t&7 of row c*32 + (t>>3). XOR bank-swizzle: logical granule
    // gl lives at phys gl ^ (row&7)  =>  thread fetches gl = (t&7) ^ ((t>>3)&7).
    const int sr = t >> 3;                       // row within chunk
    const int sg = ((t & 7) ^ ((t >> 3) & 7));   // logical granule (k/8)
    const unsigned short* ag = A + (size_t)(m0 + sr) * K + sg * 8;
    const unsigned short* bg = B + (size_t)(n0 + sr) * K + sg * 8;
    unsigned short* la = At + t * 8;
    unsigned short* lb = Bt + t * 8;

    // Fragment read: row = wm|wn + i*16 + fr (row&7 == fr&7); logical granule
    // sub*4 + (l>>4) -> phys = (sub*4 + (l>>4)) ^ (fr&7). Per-instr: 8 bank-groups
    // x 2 lanes each -> conflict-free.
    const int fr = l & 15;
    const int fx = fr & 7;
    const int g0 = (l >> 4);

    for (int k0 = 0; k0 < K; k0 += 64) {
#pragma unroll
        for (int c = 0; c < 4; c++) {
            async_cp16(ag + k0 + (size_t)(c * 32) * K, la + c * 2048);
            async_cp16(bg + k0 + (size_t)(c * 32) * K, lb + c * 2048);
        }
        __syncthreads();
#pragma unroll
        for (int sub = 0; sub < 2; sub++) {
            const int fo = ((sub * 4 + g0) ^ fx) << 3;
            short8 af[4], bf[4];
#pragma unroll
            for (int i = 0; i < 4; i++)
                af[i] = *(const short8*)(At + (wm + i * 16 + fr) * 64 + fo);
#pragma unroll
            for (int i = 0; i < 4; i++)
                bf[i] = *(const short8*)(Bt + (wn + i * 16 + fr) * 64 + fo);
#pragma unroll
            for (int i = 0; i < 4; i++)
#pragma unroll
                for (int j = 0; j < 4; j++)
                    acc[i][j] = __builtin_amdgcn_mfma_f32_16x16x32_bf16(af[i], bf[j], acc[i][j], 0, 0, 0);
        }
        __syncthreads();
    }

    // epilogue: D[m][n] lane map: n = l&15, m = (l>>4)*4 + reg
    const int er = (l >> 4) << 2;
    const int ec = l & 15;
#pragma unroll
    for (int j = 0; j < 4; j++) {
        const int col = n0 + wn + j * 16 + ec;
        const float bb = bias[col];
#pragma unroll
        for (int i = 0; i < 4; i++) {
            const int rowb = m0 + wm + i * 16 + er;
#pragma unroll
            for (int r = 0; r < 4; r++) {
                const int row = rowb + r;
                float v = acc[i][j][r] + bb;
                const size_t idx = (size_t)row * N + col;
                if (EPI == 0) {
                    if (col < 2048) v = elu1(v);
                    Cbf[idx] = f2bf(v);
                } else if (EPI == 2) {
                    Cbf[idx] = f2bf(gelu_fast(v));
                } else if (EPI == 3) {
                    Cbf[idx] = f2bf(v + resid[idx]);
                } else {
                    Cf32[idx] = v + bf2f(residb[idx]);
                }
            }
        }
    }
}

// ---------------- kv[e][d] = sum_n kf[n][e] v[n][d]; z[e] = sum_n kf[n][e] ----------------
__global__ __launch_bounds__(256)
void kv_kernel(const unsigned short* __restrict__ qkv, float* __restrict__ kvz) {
    const int bh = blockIdx.x;     // 0..63
    const int chunk = blockIdx.y;  // 0..7, 512 tokens each
    const int b = bh >> 4, h = bh & 15;
    const int t = threadIdx.x;
    __shared__ float kf[64][68];
    __shared__ float vv[64][68];
    const int te = t >> 4, td = t & 15;
    float acc[4][4];
#pragma unroll
    for (int i = 0; i < 4; i++)
#pragma unroll
        for (int j = 0; j < 4; j++) acc[i][j] = 0.f;
    float zacc = 0.f;
    const size_t base = (size_t)b * 4096 * 3072 + (size_t)chunk * 512 * 3072;
    const int koff = 1024 + h * 64;
    const int voff = 2048 + h * 64;
    const int rl = t >> 3, seg = t & 7;

    for (int s = 0; s < 8; s++) {
#pragma unroll
        for (int p = 0; p < 2; p++) {
            const int nl = p * 32 + rl;
            const unsigned short* rp = qkv + base + (size_t)(s * 64 + nl) * 3072;
            const uint4 kd = *(const uint4*)(rp + koff + seg * 8);
            const uint4 vd = *(const uint4*)(rp + voff + seg * 8);
            float* kdst = &kf[nl][seg * 8];
            float* vdst = &vv[nl][seg * 8];
            kdst[0] = bf2f(kd.x & 0xffff); kdst[1] = bf2f(kd.x >> 16);
            kdst[2] = bf2f(kd.y & 0xffff); kdst[3] = bf2f(kd.y >> 16);
            kdst[4] = bf2f(kd.z & 0xffff); kdst[5] = bf2f(kd.z >> 16);
            kdst[6] = bf2f(kd.w & 0xffff); kdst[7] = bf2f(kd.w >> 16);
            vdst[0] = bf2f(vd.x & 0xffff); vdst[1] = bf2f(vd.x >> 16);
            vdst[2] = bf2f(vd.y & 0xffff); vdst[3] = bf2f(vd.y >> 16);
            vdst[4] = bf2f(vd.z & 0xffff); vdst[5] = bf2f(vd.z >> 16);
            vdst[6] = bf2f(vd.w & 0xffff); vdst[7] = bf2f(vd.w >> 16);
        }
        __syncthreads();
        for (int n = 0; n < 64; n++) {
            const float4 kk = *(const float4*)&kf[n][te * 4];
            const float4 vn = *(const float4*)&vv[n][td * 4];
            const float ka[4] = {kk.x, kk.y, kk.z, kk.w};
            const float va[4] = {vn.x, vn.y, vn.z, vn.w};
#pragma unroll
            for (int i = 0; i < 4; i++)
#pragma unroll
                for (int j = 0; j < 4; j++) acc[i][j] = fmaf(ka[i], va[j], acc[i][j]);
        }
        if (t < 64) {
            for (int n = 0; n < 64; n++) zacc += kf[n][t];
        }
        __syncthreads();
    }
    float* kvp = kvz + bh * 4160;
#pragma unroll
    for (int i = 0; i < 4; i++)
#pragma unroll
        for (int j = 0; j < 4; j++)
            atomicAdd(&kvp[(te * 4 + i) * 64 + td * 4 + j], acc[i][j]);
    if (t < 64) atomicAdd(&kvp[4096 + t], zacc);
}

// ---------------- y[n][d] = (sum_e qf[n][e] kv[e][d]) / max(den, eps), store bf16 -------
__global__ __launch_bounds__(256)
void y_kernel(const unsigned short* __restrict__ qkv, const float* __restrict__ kvz,
              unsigned short* __restrict__ y) {
    const int bh = blockIdx.x, chunk = blockIdx.y;  // 64 x 32 (128 tokens/chunk)
    const int b = bh >> 4, h = bh & 15;
    const int t = threadIdx.x;
    __shared__ float kv[64][68];
    __shared__ float zs[64];
    __shared__ float qf[16][68];
    const float* kvp = kvz + bh * 4160;
#pragma unroll
    for (int p = 0; p < 4; p++) {
        const int f = (t + p * 256) * 4;
        const float4 v4 = *(const float4*)(kvp + f);
        *(float4*)&kv[f >> 6][f & 63] = v4;
    }
    if (t < 16) *(float4*)&zs[t * 4] = *(const float4*)(kvp + 4096 + t * 4);
    __syncthreads();
    const int nl = t >> 4, td = t & 15;
    const size_t base = (size_t)b * 4096 * 3072 + (size_t)chunk * 128 * 3072;
    const int qoff = h * 64;
    for (int s = 0; s < 8; s++) {
        if (t < 128) {
            const int r = t >> 3, seg = t & 7;
            const uint4 qd = *(const uint4*)(qkv + base + (size_t)(s * 16 + r) * 3072 + qoff + seg * 8);
            float* qdst = &qf[r][seg * 8];
            qdst[0] = bf2f(qd.x & 0xffff); qdst[1] = bf2f(qd.x >> 16);
            qdst[2] = bf2f(qd.y & 0xffff); qdst[3] = bf2f(qd.y >> 16);
            qdst[4] = bf2f(qd.z & 0xffff); qdst[5] = bf2f(qd.z >> 16);
            qdst[6] = bf2f(qd.w & 0xffff); qdst[7] = bf2f(qd.w >> 16);
        }
        __syncthreads();
        float a0 = 0.f, a1 = 0.f, a2 = 0.f, a3 = 0.f, den = 0.f;
        for (int e = 0; e < 64; e++) {
            const float q = qf[nl][e];
            const float4 kvv = *(const float4*)&kv[e][td * 4];
            a0 = fmaf(q, kvv.x, a0);
            a1 = fmaf(q, kvv.y, a1);
            a2 = fmaf(q, kvv.z, a2);
            a3 = fmaf(q, kvv.w, a3);
            den = fmaf(q, zs[e], den);
        }
        const float inv = 1.f / fmaxf(den, 1e-6f);
        const int tok = b * 4096 + chunk * 128 + s * 16 + nl;
        unsigned int o0 = f2bf(a0 * inv), o1 = f2bf(a1 * inv);
        unsigned int o2 = f2bf(a2 * inv), o3 = f2bf(a3 * inv);
        uint2 pk;
        pk.x = o0 | (o1 << 16);
        pk.y = o2 | (o3 << 16);
        *(uint2*)(y + (size_t)tok * 1024 + h * 64 + td * 4) = pk;
        __syncthreads();
    }
}

extern "C" void kernel_launch(void* const* d_in, const int* in_sizes, int n_in,
                              void* d_out, int out_size, void* d_ws, size_t ws_size,
                              hipStream_t stream) {
    const float* src   = (const float*)d_in[0];
    const float* qkv_w = (const float*)d_in[1];
    const float* qkv_b = (const float*)d_in[2];
    const float* out_w = (const float*)d_in[3];
    const float* out_b = (const float*)d_in[4];
    const float* w1    = (const float*)d_in[5];
    const float* b1    = (const float*)d_in[6];
    const float* w2    = (const float*)d_in[7];
    const float* b2    = (const float*)d_in[8];
    const float* g1    = (const float*)d_in[9];
    const float* be1   = (const float*)d_in[10];
    const float* g2    = (const float*)d_in[11];
    const float* be2   = (const float*)d_in[12];
    float* outp = (float*)d_out;

    char* ws = (char*)d_ws;
    unsigned short* qkvwT = (unsigned short*)(ws + 0);          // 3072x1024 bf16
    unsigned short* outwT = (unsigned short*)(ws + 6291456);    // 1024x1024 bf16
    unsigned short* w1T   = (unsigned short*)(ws + 8388608);    // 4096x1024 bf16
    unsigned short* w2T   = (unsigned short*)(ws + 16777216);   // 1024x4096 bf16
    unsigned short* bufA  = (unsigned short*)(ws + 25165824);   // qkv [16384,3072] / h [16384,4096] bf16
    unsigned short* bufB  = (unsigned short*)(ws + 159383552);  // ln1 -> y -> ln2 [16384,1024] bf16
    unsigned short* xbuf  = (unsigned short*)(ws + 192937984);  // x [16384,1024] bf16
    float*          kvz   = (float*)(ws + 260046848);           // 64*(64*64+64) fp32

    prep_kernel<<<12548, dim3(32, 8), 0, stream>>>(qkv_w, out_w, w1, w2,
                                                   qkvwT, outwT, w1T, w2T, kvz);

    // 1) ln1 = LN(src)  (fp32 in)
    ln_kernel<0><<<16384, 256, 0, stream>>>(src, g1, be1, bufB);
    // 2) qkv = ln1 @ qkv_w + b (elu+1 fused on q,k cols), bf16
    gemm_bt<0><<<dim3(24, 128), 256, 0, stream>>>(bufB, qkvwT, qkv_b, nullptr, nullptr, bufA, nullptr, 3072, 1024);
    // 3) kv, z aggregation
    kv_kernel<<<dim3(64, 8), 256, 0, stream>>>(bufA, kvz);
    // 4) y = qf@kv / den  (bf16)
    y_kernel<<<dim3(64, 32), 256, 0, stream>>>(bufA, kvz, bufB);
    // 5) x = y @ out_w + out_b + src  -> bf16 xbuf
    gemm_bt<3><<<dim3(8, 128), 256, 0, stream>>>(bufB, outwT, out_b, src, nullptr, xbuf, nullptr, 1024, 1024);
    // 6) ln2 = LN(x)  (bf16 in)
    ln_kernel<1><<<16384, 256, 0, stream>>>(xbuf, g2, be2, bufB);
    // 7) h = gelu(ln2 @ w1 + b1)  bf16
    gemm_bt<2><<<dim3(32, 128), 256, 0, stream>>>(bufB, w1T, b1, nullptr, nullptr, bufA, nullptr, 4096, 1024);
    // 8) out = h @ w2 + b2 + x  (fp32 out, bf16 resid)
    gemm_bt<4><<<dim3(8, 128), 256, 0, stream>>>(bufA, w2T, b2, nullptr, xbuf, nullptr, outp, 1024, 4096);
}